// Round 3
// baseline (54.527 us; speedup 1.0000x reference)
//
#include <hip/hip_runtime.h>

// DropBlock, two-phase:
//   K1: per-channel dilated drop-bitmask (64 rows x u64) -> d_ws   [128 KB]
//   K2: pure streaming apply: out = bit ? 0 : x  (grid-stride, no barriers)

constexpr int C = 256;

typedef float f32x4 __attribute__((ext_vector_type(4)));

// ---- K1: mask build. One block per channel, 256 threads. ----
__global__ __launch_bounds__(256)
void mask_kernel(const float* __restrict__ noise,
                 unsigned long long* __restrict__ maskbits) {
    const int c = blockIdx.x;
    __shared__ unsigned long long rowS[64];

    const int tid = threadIdx.x;
    const int lane = tid & 63;
    const int wv = tid >> 6;

    // gamma in double, matching the f64 numpy reference comparison
    const double gamma = (1.0 - 0.9) / (7.0 * 7.0) * (64.0 * 64.0) / (58.0 * 58.0);

    const float* nc = noise + (size_t)c * 4096;
    for (int h = wv; h < 64; h += 4) {
        float v = nc[h * 64 + lane];
        bool center = ((double)v < gamma) && (h >= 3) && (h <= 60)
                                          && (lane >= 3) && (lane <= 60);
        unsigned long long bits = __ballot(center);
        unsigned long long t = bits | (bits << 1) | (bits >> 1);
        unsigned long long s = t | (t << 2) | (t >> 2);
        if (lane == 0) rowS[h] = s;
    }
    __syncthreads();

    if (tid < 64) {
        int lo = tid - 3; if (lo < 0) lo = 0;
        int hi = tid + 3; if (hi > 63) hi = 63;
        unsigned long long d = 0;
        for (int hh = lo; hh <= hi; ++hh) d |= rowS[hh];
        maskbits[c * 64 + tid] = d;   // 1 = drop
    }
}

// ---- K2: barrier-free streaming apply ----
__global__ __launch_bounds__(256)
void apply_kernel(const f32x4* __restrict__ x,
                  const unsigned long long* __restrict__ maskbits,
                  f32x4* __restrict__ out, int n4) {
    const int stride = gridDim.x * 256;
    for (int i = blockIdx.x * 256 + threadIdx.x; i < n4; i += stride) {
        f32x4 v = x[i];
        // mask word: 16 f32x4 per row; mask space repeats every 2^18 f32x4
        const unsigned long long b = maskbits[(i >> 4) & 16383];
        const int w0 = (i & 15) << 2;
        v.x = ((b >> (w0 + 0)) & 1ull) ? 0.0f : v.x;
        v.y = ((b >> (w0 + 1)) & 1ull) ? 0.0f : v.y;
        v.z = ((b >> (w0 + 2)) & 1ull) ? 0.0f : v.z;
        v.w = ((b >> (w0 + 3)) & 1ull) ? 0.0f : v.w;
        __builtin_nontemporal_store(v, &out[i]);
    }
}

extern "C" void kernel_launch(void* const* d_in, const int* in_sizes, int n_in,
                              void* d_out, int out_size, void* d_ws, size_t ws_size,
                              hipStream_t stream) {
    const float* x = (const float*)d_in[0];
    const float* noise = (const float*)d_in[1];
    float* out = (float*)d_out;
    unsigned long long* maskbits = (unsigned long long*)d_ws;  // 16384 u64 = 128 KB

    mask_kernel<<<C, 256, 0, stream>>>(noise, maskbits);

    const int n4 = out_size / 4;                   // 8,388,608 f32x4
    apply_kernel<<<2048, 256, 0, stream>>>((const f32x4*)x, maskbits,
                                           (f32x4*)out, n4);
}